// Round 4
// baseline (55.297 us; speedup 1.0000x reference)
//
#include <hip/hip_runtime.h>
#include <hip/hip_bf16.h>

#define HW        1659      // 21*79
#define GLYPH_DIM 1536
#define NB        4         // batches per block in stage1
#define THREADS   256

typedef _Float16 half8  __attribute__((ext_vector_type(8)));
typedef _Float16 half2v __attribute__((ext_vector_type(2)));
typedef __fp16   fp16x2 __attribute__((ext_vector_type(2)));
typedef float    f32x4  __attribute__((ext_vector_type(4)));

__device__ __forceinline__ float tanh_f(float x) {
    // tanh(x) = 1 - 2/(e^{2x}+1); v_exp handles +-inf limits correctly
    float e = __expf(x + x);
    return fmaf(-2.0f, __builtin_amdgcn_rcpf(e + 1.0f), 1.0f);
}

__device__ __forceinline__ half8 pack8(float a0, float a1, float a2, float a3,
                                       float a4, float a5, float a6, float a7) {
    half2v p0 = __builtin_bit_cast(half2v, __builtin_amdgcn_cvt_pkrtz(a0, a1));
    half2v p1 = __builtin_bit_cast(half2v, __builtin_amdgcn_cvt_pkrtz(a2, a3));
    half2v p2 = __builtin_bit_cast(half2v, __builtin_amdgcn_cvt_pkrtz(a4, a5));
    half2v p3 = __builtin_bit_cast(half2v, __builtin_amdgcn_cvt_pkrtz(a6, a7));
    half8 r;
    r[0] = p0[0]; r[1] = p0[1]; r[2] = p1[0]; r[3] = p1[1];
    r[4] = p2[0]; r[5] = p2[1]; r[6] = p3[0]; r[7] = p3[1];
    return r;
}

// ---------------- stage 1: histogram -> sorted unique -> emb/bag/lens ----------------
__global__ __launch_bounds__(THREADS, 8) void glyph_stage1(
    const int* __restrict__ gchar, const int* __restrict__ gcol,
    const float* __restrict__ ctab, const float* __restrict__ ktab,
    float* __restrict__ out_emb, float* __restrict__ out_bag,
    int* __restrict__ lens_g)
{
    __shared__ unsigned int mask[NB][48];   // 1536 bits per batch
    __shared__ int ids[NB][64];

    const int tid = threadIdx.x;
    const int b0  = blockIdx.x * NB;

    if (tid < NB * 48) ((unsigned int*)mask)[tid] = 0u;
    __syncthreads();

    // phase A: bitmap histogram
    const int4* cp = (const int4*)(gchar + (long)b0 * HW);
    const int4* kp = (const int4*)(gcol  + (long)b0 * HW);
    const int n4 = (NB * HW) / 4;   // 1659
    for (int idx = tid; idx < n4; idx += THREADS) {
        int4 c = cp[idx];
        int4 k = kp[idx];
        int g = idx * 4;
        int id0 = c.x * 16 + k.x;
        int id1 = c.y * 16 + k.y;
        int id2 = c.z * 16 + k.z;
        int id3 = c.w * 16 + k.w;
        int bl0 = (g + 0) / HW;
        int bl1 = (g + 1) / HW;
        int bl2 = (g + 2) / HW;
        int bl3 = (g + 3) / HW;
        atomicOr(&mask[bl0][id0 >> 5], 1u << (id0 & 31));
        atomicOr(&mask[bl1][id1 >> 5], 1u << (id1 & 31));
        atomicOr(&mask[bl2][id2 >> 5], 1u << (id2 & 31));
        atomicOr(&mask[bl3][id3 >> 5], 1u << (id3 & 31));
    }
    __syncthreads();

    // phase B: first-64 sorted set bits per batch (4 half-wave groups)
    const int bl  = tid >> 5;
    const int l32 = tid & 31;
    if (tid < NB * 32) {
        unsigned long long m = 0ull;
        if (l32 < 24)
            m = ((unsigned long long)mask[bl][2 * l32 + 1] << 32) |
                (unsigned long long)mask[bl][2 * l32];
        int cnt  = __popcll(m);
        int incl = cnt;
        #pragma unroll
        for (int d = 1; d < 32; d <<= 1) {
            int nb = __shfl_up(incl, d, 32);
            if (l32 >= d) incl += nb;
        }
        int excl  = incl - cnt;
        int total = __shfl(incl, 31, 32);
        if (l32 == 0) lens_g[b0 + bl] = min(total, 64);
        ids[bl][l32]      = GLYPH_DIM;   // sentinel prefill (same-wave lockstep)
        ids[bl][l32 + 32] = GLYPH_DIM;
        unsigned long long mm = m;
        int r = excl;
        while (mm != 0ull && r < 64) {
            int bit = __builtin_ctzll(mm);
            ids[bl][r] = l32 * 64 + bit;
            ++r;
            mm &= (mm - 1ull);
        }
    }
    __syncthreads();

    // phase C: gather + write emb (f32) and bag; one (batch,row) per thread
    {
        const int eb = tid >> 6, r = tid & 63;   // NB*64 == 256
        int id = ids[eb][r];
        int ch = id >> 4;                              // pad -> 96
        int co = (id >= GLYPH_DIM) ? 16 : (id & 15);   // pad -> 16
        const float4* crow = (const float4*)(ctab + ch * 16);
        float4 c0 = crow[0], c1 = crow[1], c2 = crow[2], c3 = crow[3];
        float4 k0 = *(const float4*)(ktab + co * 4);
        float* gp = out_emb + ((long)(b0 + eb) * 64 + r) * 20;
        *(float4*)(gp + 0)  = c0;
        *(float4*)(gp + 4)  = c1;
        *(float4*)(gp + 8)  = c2;
        *(float4*)(gp + 12) = c3;
        *(float4*)(gp + 16) = k0;
        *(float2*)(out_bag + ((long)(b0 + eb) * 64 + r) * 2) =
            make_float2((float)ch, (float)co);
    }
}

// ---------------- stage 2: MFMA RNN, one wave = 16 batches ----------------
// Fragment k-map tau(g,i) = {4g..4g+3, 16+4g..19+4g}; used consistently for
// A (weights) and B (x, h) so any hardware k-permutation cancels. With this
// tau the C/D layout (col=lane&15, row=(lane>>4)*4+reg) feeds the next step's
// B-fragment with zero cross-lane movement.
__global__ __launch_bounds__(64) void glyph_rnn(
    const float* emb, const int* __restrict__ lens_g,
    const float* __restrict__ Wih, const float* __restrict__ Whh,
    const float* __restrict__ bih, const float* __restrict__ bhh,
    float* out_h)
{
    const int l = threadIdx.x;
    const int n = l & 15, g = l >> 4;
    const int b = blockIdx.x * 16 + n;

    // A-fragments (weights) and bias C-fragments
    half8 wihA0, wihA1, whhA0, whhA1;
    #pragma unroll
    for (int j = 0; j < 8; ++j) {
        int k = (j < 4) ? (4 * g + j) : (12 + 4 * g + j);   // tau(g,j)
        float wi0 = (k < 20) ? Wih[n * 20 + k] : 0.0f;
        float wi1 = (k < 20) ? Wih[(n + 16) * 20 + k] : 0.0f;
        wihA0[j] = (_Float16)wi0;
        wihA1[j] = (_Float16)wi1;
        whhA0[j] = (_Float16)Whh[n * 32 + k];
        whhA1[j] = (_Float16)Whh[(n + 16) * 32 + k];
    }
    f32x4 bias0, bias1;
    #pragma unroll
    for (int i = 0; i < 4; ++i) {
        bias0[i] = bih[4 * g + i] + bhh[4 * g + i];
        bias1[i] = bih[16 + 4 * g + i] + bhh[16 + 4 * g + i];
    }
    const int len = lens_g[b];

    const float* ep = emb + (long)b * 1280;   // 64*20
    float4 q1 = *(const float4*)(ep + 4 * g);
    float4 q2 = (g == 0) ? *(const float4*)(ep + 16) : make_float4(0, 0, 0, 0);

    f32x4 d0 = {0, 0, 0, 0}, d1 = {0, 0, 0, 0};   // h state in D layout

    for (int t = 0; t < 64; ++t) {
        // prefetch next step's x (independent of h; overrun at t=63 lands in
        // the bag region of d_out — valid memory, values unused)
        const float* np_ = ep + (t + 1) * 20;
        float4 nq1 = *(const float4*)(np_ + 4 * g);
        float4 nq2 = (g == 0) ? *(const float4*)(np_ + 16) : make_float4(0, 0, 0, 0);

        half8 xB = pack8(q1.x, q1.y, q1.z, q1.w, q2.x, q2.y, q2.z, q2.w);
        f32x4 a0 = __builtin_amdgcn_mfma_f32_16x16x32_f16(wihA0, xB, bias0, 0, 0, 0);
        f32x4 a1 = __builtin_amdgcn_mfma_f32_16x16x32_f16(wihA1, xB, bias1, 0, 0, 0);
        half8 hB = pack8(d0[0], d0[1], d0[2], d0[3], d1[0], d1[1], d1[2], d1[3]);
        a0 = __builtin_amdgcn_mfma_f32_16x16x32_f16(whhA0, hB, a0, 0, 0, 0);
        a1 = __builtin_amdgcn_mfma_f32_16x16x32_f16(whhA1, hB, a1, 0, 0, 0);

        bool upd = (t < len);
        #pragma unroll
        for (int i = 0; i < 4; ++i) {
            float h0 = tanh_f(a0[i]);
            float h1 = tanh_f(a1[i]);
            d0[i] = upd ? h0 : d0[i];
            d1[i] = upd ? h1 : d1[i];
        }
        q1 = nq1; q2 = nq2;
    }

    float* op = out_h + (long)b * 32;
    #pragma unroll
    for (int i = 0; i < 4; ++i) {
        op[4 * g + i]      = d0[i];
        op[16 + 4 * g + i] = d1[i];
    }
}

extern "C" void kernel_launch(void* const* d_in, const int* in_sizes, int n_in,
                              void* d_out, int out_size, void* d_ws, size_t ws_size,
                              hipStream_t stream) {
    const int* gchar = (const int*)d_in[0];
    const int* gcol  = (const int*)d_in[1];
    const float* ctab = (const float*)d_in[2];
    const float* ktab = (const float*)d_in[3];
    const float* Wih  = (const float*)d_in[4];
    const float* Whh  = (const float*)d_in[5];
    const float* bih  = (const float*)d_in[6];
    const float* bhh  = (const float*)d_in[7];

    const int B = in_sizes[0] / HW;          // 4096
    float* out_h   = (float*)d_out;                    // B*32
    float* out_emb = out_h + (long)B * 32;             // B*64*20
    float* out_bag = out_emb + (long)B * 64 * 20;      // B*64*2
    int*   lens_g  = (int*)d_ws;                       // B ints

    glyph_stage1<<<B / NB, THREADS, 0, stream>>>(
        gchar, gcol, ctab, ktab, out_emb, out_bag, lens_g);
    glyph_rnn<<<B / 16, 64, 0, stream>>>(
        out_emb, lens_g, Wih, Whh, bih, bhh, out_h);
}

// Round 5
// 37.536 us; speedup vs baseline: 1.4732x; 1.4732x over previous
//
#include <hip/hip_runtime.h>
#include <hip/hip_bf16.h>

#define HW        1659      // 21*79
#define GLYPH_DIM 1536
#define NBL       8         // batches per block
#define THREADS   256
#define XSTRIDE   2568      // bytes per batch in xfrag (64*40 + 8 pad, 8-aligned)

typedef _Float16 half8 __attribute__((ext_vector_type(8)));
typedef float    f32x4 __attribute__((ext_vector_type(4)));

__device__ __forceinline__ float tanh_f(float x) {
    // tanh(x) = 1 - 2/(e^{2x}+1); exp handles +-inf limits correctly
    float e = __expf(x + x);
    return fmaf(-2.0f, __builtin_amdgcn_rcpf(e + 1.0f), 1.0f);
}

__device__ __forceinline__ unsigned int pk(float a, float b) {
    return __builtin_bit_cast(unsigned int, __builtin_amdgcn_cvt_pkrtz(a, b));
}

__device__ __forceinline__ half8 h8(unsigned int a, unsigned int b,
                                    unsigned int c, unsigned int d) {
    uint4 u = make_uint4(a, b, c, d);
    return __builtin_bit_cast(half8, u);
}

// One block = NBL batches, fully fused: histogram -> sorted-unique -> emb/bag
// -> f16 x-fragments in LDS -> wave0 MFMA RNN. No inter-block communication.
__global__ __launch_bounds__(THREADS, 4) void glyph_fused(
    const int* __restrict__ gchar, const int* __restrict__ gcol,
    const float* __restrict__ ctab, const float* __restrict__ ktab,
    const float* __restrict__ Wih, const float* __restrict__ Whh,
    const float* __restrict__ bih, const float* __restrict__ bhh,
    float* __restrict__ out_h, float* __restrict__ out_emb,
    float* __restrict__ out_bag)
{
    __shared__ unsigned int   mask[NBL][48];    // 1.5 KB bitmap
    __shared__ unsigned short ids[NBL][64];     // 1 KB
    __shared__ int            lens[NBL];
    __shared__ __align__(16) unsigned char xfrag[NBL * XSTRIDE];  // 20.5 KB f16 x

    const int tid = threadIdx.x;
    const int b0  = blockIdx.x * NBL;

    // ---- wave0: preload RNN weights early (latency hides under phases A-C).
    // Fragment k-map tau(g,j) = {4g..4g+3, 16+4g..19+4g}, used consistently
    // for A (weights) and B (x,h) so the HW k-permutation cancels; with this
    // tau the D-layout (col=lane&15, row=(lane>>4)*4+reg) IS the next step's
    // B-fragment layout (zero cross-lane traffic).
    const int n = tid & 15, g = (tid >> 4) & 3;
    half8 wihA0, wihA1, whhA0, whhA1;
    f32x4 bias0 = {0, 0, 0, 0}, bias1 = {0, 0, 0, 0};
    if (tid < 64) {
        #pragma unroll
        for (int j = 0; j < 8; ++j) {
            int k = (j < 4) ? (4 * g + j) : (12 + 4 * g + j);
            wihA0[j] = (_Float16)((k < 20) ? Wih[n * 20 + k] : 0.0f);
            wihA1[j] = (_Float16)((k < 20) ? Wih[(n + 16) * 20 + k] : 0.0f);
            whhA0[j] = (_Float16)Whh[n * 32 + k];
            whhA1[j] = (_Float16)Whh[(n + 16) * 32 + k];
        }
        #pragma unroll
        for (int i = 0; i < 4; ++i) {
            bias0[i] = bih[4 * g + i] + bhh[4 * g + i];
            bias1[i] = bih[16 + 4 * g + i] + bhh[16 + 4 * g + i];
        }
    }

    // ---- zero bitmasks (NBL*48 = 384 words) ----
    for (int w = tid; w < NBL * 48; w += THREADS)
        ((unsigned int*)mask)[w] = 0u;
    __syncthreads();

    // ---- phase A: bitmap histogram ----
    const int4* cp = (const int4*)(gchar + (long)b0 * HW);
    const int4* kp = (const int4*)(gcol  + (long)b0 * HW);
    const int n4 = (NBL * HW) / 4;   // 3318
    for (int idx = tid; idx < n4; idx += THREADS) {
        int4 c = cp[idx];
        int4 k = kp[idx];
        int gg  = idx * 4;
        int bl0 = gg / HW;               // magic-mul div (HW is constant)
        int rem = gg - bl0 * HW;
        int bl1 = bl0 + ((rem + 1) >= HW);
        int bl2 = bl0 + ((rem + 2) >= HW);
        int bl3 = bl0 + ((rem + 3) >= HW);
        int id0 = c.x * 16 + k.x;
        int id1 = c.y * 16 + k.y;
        int id2 = c.z * 16 + k.z;
        int id3 = c.w * 16 + k.w;
        atomicOr(&mask[bl0][id0 >> 5], 1u << (id0 & 31));
        atomicOr(&mask[bl1][id1 >> 5], 1u << (id1 & 31));
        atomicOr(&mask[bl2][id2 >> 5], 1u << (id2 & 31));
        atomicOr(&mask[bl3][id3 >> 5], 1u << (id3 & 31));
    }
    __syncthreads();

    // ---- phase B: first-64 sorted set bits per batch (8 half-wave groups,
    //      NBL*32 == 256 == THREADS exactly) ----
    {
        const int bl  = tid >> 5;
        const int l32 = tid & 31;
        unsigned long long m = 0ull;
        if (l32 < 24)
            m = ((unsigned long long)mask[bl][2 * l32 + 1] << 32) |
                (unsigned long long)mask[bl][2 * l32];
        int cnt  = __popcll(m);
        int incl = cnt;
        #pragma unroll
        for (int d = 1; d < 32; d <<= 1) {
            int nb = __shfl_up(incl, d, 32);
            if (l32 >= d) incl += nb;
        }
        int excl  = incl - cnt;
        int total = __shfl(incl, 31, 32);
        if (l32 == 0) lens[bl] = min(total, 64);
        ids[bl][l32]      = GLYPH_DIM;   // sentinel prefill (same-wave order)
        ids[bl][l32 + 32] = GLYPH_DIM;
        unsigned long long mm = m;
        int r = excl;
        while (mm != 0ull && r < 64) {
            int bit = __builtin_ctzll(mm);
            ids[bl][r] = (unsigned short)(l32 * 64 + bit);
            ++r;
            mm &= (mm - 1ull);
        }
    }
    __syncthreads();

    // ---- phase C: gather tables -> global emb/bag (f32) + LDS x-frags (f16) ----
    for (int e = tid; e < NBL * 64; e += THREADS) {   // 2 rows/thread
        int nb = e >> 6, r = e & 63;
        int id = ids[nb][r];
        int ch = id >> 4;                              // pad -> 96
        int co = (id >= GLYPH_DIM) ? 16 : (id & 15);   // pad -> 16
        const float4* crow = (const float4*)(ctab + ch * 16);
        float4 c0 = crow[0], c1 = crow[1], c2 = crow[2], c3 = crow[3];
        float4 k0 = *(const float4*)(ktab + co * 4);
        float* gp = out_emb + ((long)(b0 + nb) * 64 + r) * 20;
        *(float4*)(gp + 0)  = c0;
        *(float4*)(gp + 4)  = c1;
        *(float4*)(gp + 8)  = c2;
        *(float4*)(gp + 12) = c3;
        *(float4*)(gp + 16) = k0;
        *(float2*)(out_bag + ((long)(b0 + nb) * 64 + r) * 2) =
            make_float2((float)ch, (float)co);
        unsigned char* xp = &xfrag[nb * XSTRIDE + r * 40];
        *(uint2*)(xp + 0)  = make_uint2(pk(c0.x, c0.y), pk(c0.z, c0.w));
        *(uint2*)(xp + 8)  = make_uint2(pk(c1.x, c1.y), pk(c1.z, c1.w));
        *(uint2*)(xp + 16) = make_uint2(pk(c2.x, c2.y), pk(c2.z, c2.w));
        *(uint2*)(xp + 24) = make_uint2(pk(c3.x, c3.y), pk(c3.z, c3.w));
        *(uint2*)(xp + 32) = make_uint2(pk(k0.x, k0.y), pk(k0.z, k0.w));
    }
    __syncthreads();

    // ---- phase D: wave0 MFMA RNN over this block's NBL batches ----
    if (tid < 64) {
        const int nc  = n & (NBL - 1);        // cols >= NBL duplicate batch 0-7
        const int len = lens[nc];
        const unsigned char* xb = &xfrag[nc * XSTRIDE];
        f32x4 d0 = {0, 0, 0, 0}, d1 = {0, 0, 0, 0};
        #pragma unroll 4
        for (int t = 0; t < 64; ++t) {
            const unsigned char* xp = xb + t * 40;
            uint2 lo = *(const uint2*)(xp + 8 * g);
            uint2 hi = (g == 0) ? *(const uint2*)(xp + 32) : make_uint2(0u, 0u);
            half8 xB = h8(lo.x, lo.y, hi.x, hi.y);
            f32x4 a0 = __builtin_amdgcn_mfma_f32_16x16x32_f16(wihA0, xB, bias0, 0, 0, 0);
            f32x4 a1 = __builtin_amdgcn_mfma_f32_16x16x32_f16(wihA1, xB, bias1, 0, 0, 0);
            half8 hB = h8(pk(d0[0], d0[1]), pk(d0[2], d0[3]),
                          pk(d1[0], d1[1]), pk(d1[2], d1[3]));
            a0 = __builtin_amdgcn_mfma_f32_16x16x32_f16(whhA0, hB, a0, 0, 0, 0);
            a1 = __builtin_amdgcn_mfma_f32_16x16x32_f16(whhA1, hB, a1, 0, 0, 0);
            bool upd = (t < len);
            #pragma unroll
            for (int i = 0; i < 4; ++i) {
                float h0 = tanh_f(a0[i]);
                float h1 = tanh_f(a1[i]);
                d0[i] = upd ? h0 : d0[i];
                d1[i] = upd ? h1 : d1[i];
            }
        }
        if (n < NBL) {
            float* op = out_h + (long)(b0 + n) * 32;
            #pragma unroll
            for (int i = 0; i < 4; ++i) {
                op[4 * g + i]      = d0[i];
                op[16 + 4 * g + i] = d1[i];
            }
        }
    }
}

extern "C" void kernel_launch(void* const* d_in, const int* in_sizes, int n_in,
                              void* d_out, int out_size, void* d_ws, size_t ws_size,
                              hipStream_t stream) {
    const int* gchar = (const int*)d_in[0];
    const int* gcol  = (const int*)d_in[1];
    const float* ctab = (const float*)d_in[2];
    const float* ktab = (const float*)d_in[3];
    const float* Wih  = (const float*)d_in[4];
    const float* Whh  = (const float*)d_in[5];
    const float* bih  = (const float*)d_in[6];
    const float* bhh  = (const float*)d_in[7];

    const int B = in_sizes[0] / HW;          // 4096
    float* out_h   = (float*)d_out;                    // B*32
    float* out_emb = out_h + (long)B * 32;             // B*64*20
    float* out_bag = out_emb + (long)B * 64 * 20;      // B*64*2

    glyph_fused<<<B / NBL, THREADS, 0, stream>>>(
        gchar, gcol, ctab, ktab, Wih, Whh, bih, bhh, out_h, out_emb, out_bag);
}